// Round 6
// baseline (183.370 us; speedup 1.0000x reference)
//
#include <hip/hip_runtime.h>
#include <math.h>

#define TSEQ 2048
#define NB   2
#define DM   1024
#define NH   16
#define DH   64
#define GN_EPS 1e-5f

typedef short v8s __attribute__((ext_vector_type(8)));
typedef short v4s __attribute__((ext_vector_type(4)));
typedef float v4f __attribute__((ext_vector_type(4)));

__device__ __forceinline__ short f2bf(float f) {
    union { float f; unsigned u; } c; c.f = f;
    unsigned u = c.u;
    unsigned r = (u + 0x7fffu + ((u >> 16) & 1u)) >> 16;   // RNE
    return (short)r;
}

// pack two f32 -> two bf16 in one instruction (no builtin on gfx950)
__device__ __forceinline__ unsigned cvtpk_bf16(float lo, float hi) {
    unsigned r;
    asm("v_cvt_pk_bf16_f32 %0, %1, %2" : "=v"(r) : "v"(lo), "v"(hi));
    return r;
}

// async global->LDS, 16B per lane.  LDS dest = wave-uniform base + lane*16.
__device__ __forceinline__ void gl_lds16(const void* g, void* l) {
    __builtin_amdgcn_global_load_lds(
        (const __attribute__((address_space(1))) void*)g,
        (__attribute__((address_space(3))) void*)l, 16, 0, 0);
}

// ---------------------------------------------------------------------------
// cast x and the 4 weight matrices to bf16; zero the GN stats
// ---------------------------------------------------------------------------
__global__ __launch_bounds__(256) void cast_kernel(
    const float* __restrict__ x,
    const float* __restrict__ Wq, const float* __restrict__ Wk,
    const float* __restrict__ Wv, const float* __restrict__ Wo,
    short* __restrict__ xbf, short* __restrict__ wbf, float* __restrict__ stats)
{
    if (blockIdx.x == 0 && threadIdx.x < 64) stats[threadIdx.x] = 0.0f;
    const int NX = NB * TSEQ * DM;            // 4,194,304
    const int NW = DM * DM;                   // 1,048,576
    const int total4 = (NX + 4 * NW) / 4;     // 2,097,152
    for (int i = blockIdx.x * 256 + threadIdx.x; i < total4;
         i += gridDim.x * 256) {
        int e = i * 4;
        const float* src; short* dst;
        if (e < NX) { src = x + e; dst = xbf + e; }
        else {
            int o = e - NX;
            int w = o >> 20;
            int r = o & (NW - 1);
            src = (w == 0 ? Wq : w == 1 ? Wk : w == 2 ? Wv : Wo) + r;
            dst = wbf + o;
        }
        v4f v = *(const v4f*)src;
        v4s s;
        #pragma unroll
        for (int j = 0; j < 4; ++j) s[j] = f2bf(v[j]);
        *(v4s*)dst = s;
    }
}

// ---------------------------------------------------------------------------
// QKV projection, bf16 MFMA, m97-style: 128x128 tile, BK=64, single 32KB
// LDS buffer staged via global_load_lds(16B) with linear dest + pre-swizzled
// source; ds_read_b128 with the same XOR swizzle (conflict-free).
// grid (8, 32, 3).  z=0: Q' = Q * gamma_h^(t&63) / 8;  z=1: K' * gamma^-(t&63)
//                   z=2: V transposed -> Vt[b][h*64+d][t]
// ---------------------------------------------------------------------------
__global__ __launch_bounds__(256, 3) void gemm_qkv_mfma(
    const short* __restrict__ xbf, const short* __restrict__ wbf,
    short* __restrict__ Qb, short* __restrict__ Kb, short* __restrict__ Vt)
{
    const int z = blockIdx.z;
    const short* __restrict__ Bmat = wbf + (size_t)z * (DM * DM);
    const int n0 = blockIdx.x * 128, m0 = blockIdx.y * 128;
    const int t = threadIdx.x, l = t & 63, w = t >> 6;
    const int wr = (w >> 1) * 64, wc = (w & 1) * 64;
    const int lr = l & 15, g = l >> 4, lg4 = g * 4;

    __shared__ short As[128 * 64];
    __shared__ short Bs[128 * 64];

    v4f acc[4][4];
    #pragma unroll
    for (int i = 0; i < 4; ++i)
        #pragma unroll
        for (int j = 0; j < 4; ++j) acc[i][j] = (v4f){0.f, 0.f, 0.f, 0.f};

    const char* Agp = (const char*)(xbf  + (size_t)m0 * DM);
    const char* Bgp = (const char*)(Bmat + (size_t)n0 * DM);

    // staging constants: chunk i = p*256+t; dest linear, source pre-swizzled
    int soff[4], sdst[4];
    #pragma unroll
    for (int p = 0; p < 4; ++p) {
        int i = p * 256 + t;
        int row = i >> 3;
        int cp  = (i & 7) * 16;
        soff[p] = row * (DM * 2) + (cp ^ ((row & 7) << 4));
        sdst[p] = (p * 256 + (t & 192)) * 16;      // wave-uniform base
    }
    const int swz = (lr & 7) << 4;

    for (int kt = 0; kt < DM / 64; ++kt) {
        const int kb = kt * 128;                    // k0 byte offset in row
        #pragma unroll
        for (int p = 0; p < 4; ++p) {
            gl_lds16(Agp + (size_t)soff[p] + kb, (char*)As + sdst[p]);
            gl_lds16(Bgp + (size_t)soff[p] + kb, (char*)Bs + sdst[p]);
        }
        asm volatile("s_waitcnt vmcnt(0)" ::: "memory");
        __syncthreads();

        v8s bfr[4][2];
        #pragma unroll
        for (int j = 0; j < 4; ++j) {
            int rowb = wc + j * 16 + lr;
            #pragma unroll
            for (int ks = 0; ks < 2; ++ks)
                bfr[j][ks] = *(const v8s*)((const char*)Bs + rowb * 128
                               + ((ks * 64 + g * 16) ^ swz));
        }
        #pragma unroll
        for (int i = 0; i < 4; ++i) {
            int rowa = wr + i * 16 + lr;
            v8s a0 = *(const v8s*)((const char*)As + rowa * 128 + ((g * 16) ^ swz));
            v8s a1 = *(const v8s*)((const char*)As + rowa * 128 + ((64 + g * 16) ^ swz));
            #pragma unroll
            for (int j = 0; j < 4; ++j) {
                acc[i][j] = __builtin_amdgcn_mfma_f32_16x16x32_bf16(
                    a0, bfr[j][0], acc[i][j], 0, 0, 0);
                acc[i][j] = __builtin_amdgcn_mfma_f32_16x16x32_bf16(
                    a1, bfr[j][1], acc[i][j], 0, 0, 0);
            }
        }
        __syncthreads();
    }

    if (z < 2) {
        short* __restrict__ O = (z == 0) ? Qb : Kb;
        const float sgn = (z == 0) ? 1.0f : -1.0f;
        const float c0  = (z == 0) ? -3.0f : 0.0f;     // fold 1/8 into Q
        float l2gj[4];
        #pragma unroll
        for (int j = 0; j < 4; ++j) {
            int hh = (n0 + wc + j * 16 + lr) >> 6;
            l2gj[j] = sgn * log2f(1.0f - exp2f(-5.0f - (float)hh));
        }
        #pragma unroll
        for (int i = 0; i < 4; ++i) {
            int row = m0 + wr + i * 16 + lg4;
            #pragma unroll
            for (int j = 0; j < 4; ++j) {
                int col = n0 + wc + j * 16 + lr;
                #pragma unroll
                for (int r = 0; r < 4; ++r) {
                    int tl = (row + r) & 63;
                    float fac = exp2f(fmaf(l2gj[j], (float)tl, c0));
                    O[(size_t)(row + r) * DM + col] = f2bf(acc[i][j][r] * fac);
                }
            }
        }
    } else {
        #pragma unroll
        for (int i = 0; i < 4; ++i) {
            int row  = m0 + wr + i * 16 + lg4;
            int bidx = row >> 11, tb = row & (TSEQ - 1);
            #pragma unroll
            for (int j = 0; j < 4; ++j) {
                int col = n0 + wc + j * 16 + lr;
                v4s pk;
                #pragma unroll
                for (int r = 0; r < 4; ++r) pk[r] = f2bf(acc[i][j][r]);
                *(v4s*)(Vt + ((size_t)bidx << 21) + ((size_t)col << 11) + tb) = pk;
            }
        }
    }
}

// ---------------------------------------------------------------------------
// Retention: Y = (Q K^T * gamma^(i-j) / 8) @ V, causal.  Decay prescaled
// into Q',K'; per-j-tile residual is the uniform scalar gamma^(64*dTile).
// Swapped QK (St = K.Q^T), cvt_pk + b64 swizzled LDS, PV as Y^T = V^T.S.
// PHASE-SPLIT grid: 512 blocks (2/CU -> 8 waves/CU).  Each block's 4 waves
// each own ONE 32-row half-tile: slots s = sub*4+w; idx<8 -> tile 63-s
// (long, dispatched first: LPT), idx>=8 -> tile s.  Vt loads issued right
// after QK MFMAs so their latency hides under pack/LDS.  No block barriers.
// ---------------------------------------------------------------------------
__global__ __launch_bounds__(256) void retention_mfma(
    const short* __restrict__ Qb, const short* __restrict__ Kb,
    const short* __restrict__ Vt, float* __restrict__ Y,
    float* __restrict__ stats)
{
    const int bid = blockIdx.x;                      // 0..511
    const int swz = (bid & 7) * 64 + (bid >> 3);     // XCD-chunked, bijective
    const int bh  = swz >> 4;                        // 0..31
    const int b = bh >> 4, h = bh & 15;
    const int idx = swz & 15;                        // 16 blocks per (b,h)
    const int tid = threadIdx.x, l = tid & 63, w = tid >> 6;
    const int lr = l & 15, g = l >> 4;
    const int sub  = (idx < 8) ? idx : (15 - idx);
    const int s    = sub * 4 + w;                    // slot 0..31
    const int tile = (idx < 8) ? (63 - s) : s;       // 32-row half-tile

    __shared__ short S_lds[4][2][2048];              // 32 KB per-wave dbuf
    __shared__ float tr[4][16][68];                  // epilogue transpose

    const float l2g = log2f(1.0f - exp2f(-5.0f - (float)h));
    const float g64 = exp2f(l2g * 64.0f);            // gamma^64

    const size_t kroot = (size_t)b * TSEQ * DM + h * DH;
    const size_t vroot = ((size_t)b * DM + h * DH) * TSEQ;

    const int i0  = tile * 32;
    const int jtd = tile >> 1;                       // diagonal 64-j-tile

    // Q' B-fragments (col = i = i0+ib*16+lr, k = d contiguous)
    v8s qf[2][2];
    #pragma unroll
    for (int ib = 0; ib < 2; ++ib)
        #pragma unroll
        for (int k2 = 0; k2 < 2; ++k2)
            qf[ib][k2] = *(const v8s*)(Qb + kroot
                + (size_t)(i0 + ib * 16 + lr) * DM + k2 * 32 + g * 8);

    v4f y[4][2];
    #pragma unroll
    for (int dt = 0; dt < 4; ++dt)
        #pragma unroll
        for (int ib = 0; ib < 2; ++ib) y[dt][ib] = (v4f){0.f,0.f,0.f,0.f};

    float tf = 1.0f;                                 // gamma^(64*(jtd-jt))
    for (int jt = jtd; jt >= 0; --jt) {
        const int j0 = jt * 64;
        char* Sw = (char*)&S_lds[w][jt & 1][0];

        // ---- K loads ----
        v8s kf[4][2];
        #pragma unroll
        for (int n = 0; n < 4; ++n) {
            const short* kp = Kb + kroot + (size_t)(j0 + n * 16 + lr) * DM;
            kf[n][0] = *(const v8s*)(kp + g * 8);
            kf[n][1] = *(const v8s*)(kp + 32 + g * 8);
        }

        // ---- St = K'.Q'^T : rows j, cols i ----
        v4f st[4][2];
        #pragma unroll
        for (int n = 0; n < 4; ++n)
            #pragma unroll
            for (int ib = 0; ib < 2; ++ib) {
                v4f a = (v4f){0.f, 0.f, 0.f, 0.f};
                a = __builtin_amdgcn_mfma_f32_16x16x32_bf16(kf[n][0], qf[ib][0], a, 0, 0, 0);
                a = __builtin_amdgcn_mfma_f32_16x16x32_bf16(kf[n][1], qf[ib][1], a, 0, 0, 0);
                st[n][ib] = a;
            }

        // ---- Vt prefetch (independent of S; hides under pack/LDS) ----
        v8s vf[4][2];
        #pragma unroll
        for (int dt = 0; dt < 4; ++dt)
            #pragma unroll
            for (int ks = 0; ks < 2; ++ks)
                vf[dt][ks] = *(const v8s*)(Vt + vroot
                    + (size_t)(dt * 16 + lr) * TSEQ + j0 + ks * 32 + g * 8);

        // ---- uniform tile decay + diag mask + pack + swizzled b64 LDS ----
        const bool dg = (jt == jtd);
        #pragma unroll
        for (int n = 0; n < 4; ++n)
            #pragma unroll
            for (int ib = 0; ib < 2; ++ib) {
                v4f v = st[n][ib] * tf;
                if (dg) {
                    #pragma unroll
                    for (int r = 0; r < 4; ++r)
                        if ((i0 + ib * 16 + lr) - (j0 + n * 16 + g * 4 + r) < 0)
                            v[r] = 0.0f;
                }
                unsigned u0 = cvtpk_bf16(v[0], v[1]);
                unsigned u1 = cvtpk_bf16(v[2], v[3]);
                int byte = ((ib * 16 + lr) * 128 + n * 32 + g * 8)
                           ^ ((lr & 7) << 4);
                *(unsigned long long*)(Sw + byte) =
                    (unsigned long long)u0 | ((unsigned long long)u1 << 32);
            }

        // ---- Y^T += V^T . S  (A = Vt rows d, B = S rows i, k = j) ----
        v8s sB[2][2];
        #pragma unroll
        for (int ib = 0; ib < 2; ++ib)
            #pragma unroll
            for (int ks = 0; ks < 2; ++ks) {
                int byte = ((ib * 16 + lr) * 128 + ks * 64 + g * 16)
                           ^ ((lr & 7) << 4);
                sB[ib][ks] = *(const v8s*)(Sw + byte);
            }
        #pragma unroll
        for (int dt = 0; dt < 4; ++dt)
            #pragma unroll
            for (int ks = 0; ks < 2; ++ks)
                #pragma unroll
                for (int ib = 0; ib < 2; ++ib)
                    y[dt][ib] = __builtin_amdgcn_mfma_f32_16x16x32_bf16(
                        vf[dt][ks], sB[ib][ks], y[dt][ib], 0, 0, 0);

        tf *= g64;
    }

    // ---- GN stats from regs ----
    float lsum = 0.f, lsq = 0.f;
    #pragma unroll
    for (int dt = 0; dt < 4; ++dt)
        #pragma unroll
        for (int ib = 0; ib < 2; ++ib)
            #pragma unroll
            for (int r = 0; r < 4; ++r) {
                float v = y[dt][ib][r];
                lsum += v; lsq += v * v;
            }

    // ---- un-transpose Y^T -> Y[b][t][dm] via per-wave scratch ----
    #pragma unroll
    for (int ib = 0; ib < 2; ++ib) {
        #pragma unroll
        for (int dt = 0; dt < 4; ++dt)
            #pragma unroll
            for (int r = 0; r < 4; ++r)
                tr[w][lr][dt * 16 + g * 4 + r] = y[dt][ib][r];
        __builtin_amdgcn_sched_barrier(0);
        #pragma unroll
        for (int u = 0; u < 4; ++u) {
            v4f val = *(const v4f*)&tr[w][lr][g * 16 + u * 4];
            *(v4f*)&Y[(size_t)(b * TSEQ + i0 + ib * 16 + lr) * DM
                      + h * DH + g * 16 + u * 4] = val;
        }
        __builtin_amdgcn_sched_barrier(0);
    }

    // ---- per-wave stats -> atomics ----
    #pragma unroll
    for (int m = 32; m; m >>= 1) {
        lsum += __shfl_xor(lsum, m, 64);
        lsq  += __shfl_xor(lsq,  m, 64);
    }
    if (l == 0) {
        atomicAdd(&stats[b * NH + h],      lsum);
        atomicAdd(&stats[32 + b * NH + h], lsq);
    }
}

// ---------------------------------------------------------------------------
// GroupNorm finalize: per (b, channel) scale/shift
// ---------------------------------------------------------------------------
__global__ __launch_bounds__(256) void gn_finalize(
    const float* __restrict__ stats,
    const float* __restrict__ gnw, const float* __restrict__ gnb,
    float* __restrict__ scale, float* __restrict__ shift)
{
    int idx = blockIdx.x * 256 + threadIdx.x;
    if (idx >= NB * DM) return;
    int bb = idx >> 10;
    int c  = idx & (DM - 1);
    int hh = c >> 6;
    const float n = (float)(DH * TSEQ);
    float mean = stats[bb * NH + hh] / n;
    float var  = stats[32 + bb * NH + hh] / n - mean * mean;
    float rstd = rsqrtf(var + GN_EPS);
    float sc = rstd * gnw[c];
    scale[idx] = sc;
    shift[idx] = gnb[c] - mean * sc;
}

// ---------------------------------------------------------------------------
// Apply GN -> bf16 (input to the output projection)
// ---------------------------------------------------------------------------
__global__ __launch_bounds__(256) void gn_apply(
    const float* __restrict__ Y, const float* __restrict__ scale,
    const float* __restrict__ shift, short* __restrict__ Ybf)
{
    const int total4 = (NB * TSEQ * DM) / 4;   // 1,048,576
    for (int i = blockIdx.x * 256 + threadIdx.x; i < total4;
         i += gridDim.x * 256) {
        int e = i * 4;
        int c = e & (DM - 1);
        int bb = e >> 21;
        v4f yv = *(const v4f*)(Y + e);
        v4f sc = *(const v4f*)(scale + bb * DM + c);
        v4f sh = *(const v4f*)(shift + bb * DM + c);
        v4s o;
        #pragma unroll
        for (int j = 0; j < 4; ++j) o[j] = f2bf(yv[j] * sc[j] + sh[j]);
        *(v4s*)(Ybf + e) = o;
    }
}

// ---------------------------------------------------------------------------
// Output projection: out = Ybf @ Wo^T, fp32 out.  Same m97-style main loop.
// ---------------------------------------------------------------------------
__global__ __launch_bounds__(256, 3) void gemm_out_mfma(
    const short* __restrict__ Ybf, const short* __restrict__ Wob,
    float* __restrict__ out)
{
    const int n0 = blockIdx.x * 128, m0 = blockIdx.y * 128;
    const int t = threadIdx.x, l = t & 63, w = t >> 6;
    const int wr = (w >> 1) * 64, wc = (w & 1) * 64;
    const int lr = l & 15, g = l >> 4;

    __shared__ short As[128 * 64];
    __shared__ short Bs[128 * 64];

    v4f acc[4][4];
    #pragma unroll
    for (int i = 0; i < 4; ++i)
        #pragma unroll
        for (int j = 0; j < 4; ++j) acc[i][j] = (v4f){0.f, 0.f, 0.f, 0.f};

    const char* Agp = (const char*)(Ybf + (size_t)m0 * DM);
    const char* Bgp = (const char*)(Wob + (size_t)n0 * DM);

    int soff[4], sdst[4];
    #pragma unroll
    for (int p = 0; p < 4; ++p) {
        int i = p * 256 + t;
        int row = i >> 3;
        int cp  = (i & 7) * 16;
        soff[p] = row * (DM * 2) + (cp ^ ((row & 7) << 4));
        sdst[p] = (p * 256 + (t & 192)) * 16;
    }
    const int swz = (lr & 7) << 4;

    for (int kt = 0; kt < DM / 64; ++kt) {
        const int kb = kt * 128;
        #pragma unroll
        for (int p = 0; p < 4; ++p) {
            gl_lds16(Agp + (size_t)soff[p] + kb, (char*)As + sdst[p]);
            gl_lds16(Bgp + (size_t)soff[p] + kb, (char*)Bs + sdst[p]);
        }
        asm volatile("s_waitcnt vmcnt(0)" ::: "memory");
        __syncthreads();

        v8s bfr[4][2];
        #pragma unroll
        for (int j = 0; j < 4; ++j) {
            int rowb = wc + j * 16 + lr;
            #pragma unroll
            for (int ks = 0; ks < 2; ++ks)
                bfr[j][ks] = *(const v8s*)((const char*)Bs + rowb * 128
                               + ((ks * 64 + g * 16) ^ swz));
        }
        #pragma unroll
        for (int i = 0; i < 4; ++i) {
            int rowa = wr + i * 16 + lr;
            v8s a0 = *(const v8s*)((const char*)As + rowa * 128 + ((g * 16) ^ swz));
            v8s a1 = *(const v8s*)((const char*)As + rowa * 128 + ((64 + g * 16) ^ swz));
            #pragma unroll
            for (int j = 0; j < 4; ++j) {
                acc[i][j] = __builtin_amdgcn_mfma_f32_16x16x32_bf16(
                    a0, bfr[j][0], acc[i][j], 0, 0, 0);
                acc[i][j] = __builtin_amdgcn_mfma_f32_16x16x32_bf16(
                    a1, bfr[j][1], acc[i][j], 0, 0, 0);
            }
        }
        __syncthreads();
    }

    #pragma unroll
    for (int i = 0; i < 4; ++i) {
        int row = m0 + wr + i * 16 + g * 4;
        #pragma unroll
        for (int j = 0; j < 4; ++j) {
            int col = n0 + wc + j * 16 + lr;
            #pragma unroll
            for (int r = 0; r < 4; ++r)
                out[(size_t)(row + r) * DM + col] = acc[i][j][r];
        }
    }
}

// ---------------------------------------------------------------------------
extern "C" void kernel_launch(void* const* d_in, const int* in_sizes, int n_in,
                              void* d_out, int out_size, void* d_ws, size_t ws_size,
                              hipStream_t stream)
{
    const float* x   = (const float*)d_in[0];
    const float* Wq  = (const float*)d_in[1];
    const float* Wk  = (const float*)d_in[2];
    const float* Wv  = (const float*)d_in[3];
    const float* Wo  = (const float*)d_in[4];
    const float* gnw = (const float*)d_in[5];
    const float* gnb = (const float*)d_in[6];
    float* out = (float*)d_out;

    // workspace carve (bytes)
    char* wsb = (char*)d_ws;
    size_t o = 0;
    float* Y    = (float*)(wsb + o); o += (size_t)NB * TSEQ * DM * 4;
    short* Qb   = (short*)(wsb + o); o += (size_t)NB * TSEQ * DM * 2;
    short* Kb   = (short*)(wsb + o); o += (size_t)NB * TSEQ * DM * 2;
    short* Vt   = (short*)(wsb + o); o += (size_t)NB * TSEQ * DM * 2;
    short* xbf  = (short*)(wsb + o); o += (size_t)NB * TSEQ * DM * 2;
    short* wbf  = (short*)(wsb + o); o += (size_t)4 * DM * DM * 2;
    short* Ybf  = (short*)(wsb + o); o += (size_t)NB * TSEQ * DM * 2;
    float* stats = (float*)(wsb + o); o += 256;
    float* scale = (float*)(wsb + o); o += (size_t)NB * DM * 4;
    float* shift = (float*)(wsb + o); o += (size_t)NB * DM * 4;
    if (ws_size < o) return;

    cast_kernel<<<2048, 256, 0, stream>>>(x, Wq, Wk, Wv, Wo, xbf, wbf, stats);
    gemm_qkv_mfma<<<dim3(DM / 128, (NB * TSEQ) / 128, 3), 256, 0, stream>>>(
        xbf, wbf, Qb, Kb, Vt);
    retention_mfma<<<dim3(512), 256, 0, stream>>>(
        Qb, Kb, Vt, Y, stats);
    gn_finalize<<<dim3((NB * DM + 255) / 256), 256, 0, stream>>>(
        stats, gnw, gnb, scale, shift);
    gn_apply<<<2048, 256, 0, stream>>>(Y, scale, shift, Ybf);
    gemm_out_mfma<<<dim3(DM / 128, (NB * TSEQ) / 128), 256, 0, stream>>>(
        Ybf, wbf + 3 * (size_t)DM * DM, out);
}

// Round 7
// 125.386 us; speedup vs baseline: 1.4624x; 1.4624x over previous
//
#include <hip/hip_runtime.h>
#include <math.h>

#define TSEQ 2048
#define NB   2
#define DM   1024
#define NH   16
#define DH   64
#define GN_EPS 1e-5f

typedef short v8s __attribute__((ext_vector_type(8)));
typedef short v4s __attribute__((ext_vector_type(4)));
typedef float v4f __attribute__((ext_vector_type(4)));

__device__ __forceinline__ short f2bf(float f) {
    union { float f; unsigned u; } c; c.f = f;
    unsigned u = c.u;
    unsigned r = (u + 0x7fffu + ((u >> 16) & 1u)) >> 16;   // RNE
    return (short)r;
}

// pack two f32 -> two bf16 in one instruction (no builtin on gfx950)
__device__ __forceinline__ unsigned cvtpk_bf16(float lo, float hi) {
    unsigned r;
    asm("v_cvt_pk_bf16_f32 %0, %1, %2" : "=v"(r) : "v"(lo), "v"(hi));
    return r;
}

// async global->LDS, 16B per lane.  LDS dest = wave-uniform base + lane*16.
__device__ __forceinline__ void gl_lds16(const void* g, void* l) {
    __builtin_amdgcn_global_load_lds(
        (const __attribute__((address_space(1))) void*)g,
        (__attribute__((address_space(3))) void*)l, 16, 0, 0);
}

// ---------------------------------------------------------------------------
// cast x and the 4 weight matrices to bf16; zero the GN stats
// ---------------------------------------------------------------------------
__global__ __launch_bounds__(256) void cast_kernel(
    const float* __restrict__ x,
    const float* __restrict__ Wq, const float* __restrict__ Wk,
    const float* __restrict__ Wv, const float* __restrict__ Wo,
    short* __restrict__ xbf, short* __restrict__ wbf, float* __restrict__ stats)
{
    if (blockIdx.x == 0 && threadIdx.x < 64) stats[threadIdx.x] = 0.0f;
    const int NX = NB * TSEQ * DM;            // 4,194,304
    const int NW = DM * DM;                   // 1,048,576
    const int total4 = (NX + 4 * NW) / 4;     // 2,097,152
    for (int i = blockIdx.x * 256 + threadIdx.x; i < total4;
         i += gridDim.x * 256) {
        int e = i * 4;
        const float* src; short* dst;
        if (e < NX) { src = x + e; dst = xbf + e; }
        else {
            int o = e - NX;
            int w = o >> 20;
            int r = o & (NW - 1);
            src = (w == 0 ? Wq : w == 1 ? Wk : w == 2 ? Wv : Wo) + r;
            dst = wbf + o;
        }
        v4f v = *(const v4f*)src;
        v4s s;
        #pragma unroll
        for (int j = 0; j < 4; ++j) s[j] = f2bf(v[j]);
        *(v4s*)dst = s;
    }
}

// ---------------------------------------------------------------------------
// QKV projection, bf16 MFMA, m97-style: 128x128 tile, BK=64, single 32KB
// LDS buffer staged via global_load_lds(16B) with linear dest + pre-swizzled
// source; ds_read_b128 with the same XOR swizzle (conflict-free).
// grid (8, 32, 3).  z=0: Q' = Q * gamma_h^(t&63) / 8;  z=1: K' * gamma^-(t&63)
//                   z=2: V transposed -> Vt[b][h*64+d][t]
// ---------------------------------------------------------------------------
__global__ __launch_bounds__(256, 3) void gemm_qkv_mfma(
    const short* __restrict__ xbf, const short* __restrict__ wbf,
    short* __restrict__ Qb, short* __restrict__ Kb, short* __restrict__ Vt)
{
    const int z = blockIdx.z;
    const short* __restrict__ Bmat = wbf + (size_t)z * (DM * DM);
    const int n0 = blockIdx.x * 128, m0 = blockIdx.y * 128;
    const int t = threadIdx.x, l = t & 63, w = t >> 6;
    const int wr = (w >> 1) * 64, wc = (w & 1) * 64;
    const int lr = l & 15, g = l >> 4, lg4 = g * 4;

    __shared__ short As[128 * 64];
    __shared__ short Bs[128 * 64];

    v4f acc[4][4];
    #pragma unroll
    for (int i = 0; i < 4; ++i)
        #pragma unroll
        for (int j = 0; j < 4; ++j) acc[i][j] = (v4f){0.f, 0.f, 0.f, 0.f};

    const char* Agp = (const char*)(xbf  + (size_t)m0 * DM);
    const char* Bgp = (const char*)(Bmat + (size_t)n0 * DM);

    // staging constants: chunk i = p*256+t; dest linear, source pre-swizzled
    int soff[4], sdst[4];
    #pragma unroll
    for (int p = 0; p < 4; ++p) {
        int i = p * 256 + t;
        int row = i >> 3;
        int cp  = (i & 7) * 16;
        soff[p] = row * (DM * 2) + (cp ^ ((row & 7) << 4));
        sdst[p] = (p * 256 + (t & 192)) * 16;      // wave-uniform base
    }
    const int swz = (lr & 7) << 4;

    for (int kt = 0; kt < DM / 64; ++kt) {
        const int kb = kt * 128;                    // k0 byte offset in row
        #pragma unroll
        for (int p = 0; p < 4; ++p) {
            gl_lds16(Agp + (size_t)soff[p] + kb, (char*)As + sdst[p]);
            gl_lds16(Bgp + (size_t)soff[p] + kb, (char*)Bs + sdst[p]);
        }
        asm volatile("s_waitcnt vmcnt(0)" ::: "memory");
        __syncthreads();

        v8s bfr[4][2];
        #pragma unroll
        for (int j = 0; j < 4; ++j) {
            int rowb = wc + j * 16 + lr;
            #pragma unroll
            for (int ks = 0; ks < 2; ++ks)
                bfr[j][ks] = *(const v8s*)((const char*)Bs + rowb * 128
                               + ((ks * 64 + g * 16) ^ swz));
        }
        #pragma unroll
        for (int i = 0; i < 4; ++i) {
            int rowa = wr + i * 16 + lr;
            v8s a0 = *(const v8s*)((const char*)As + rowa * 128 + ((g * 16) ^ swz));
            v8s a1 = *(const v8s*)((const char*)As + rowa * 128 + ((64 + g * 16) ^ swz));
            #pragma unroll
            for (int j = 0; j < 4; ++j) {
                acc[i][j] = __builtin_amdgcn_mfma_f32_16x16x32_bf16(
                    a0, bfr[j][0], acc[i][j], 0, 0, 0);
                acc[i][j] = __builtin_amdgcn_mfma_f32_16x16x32_bf16(
                    a1, bfr[j][1], acc[i][j], 0, 0, 0);
            }
        }
        __syncthreads();
    }

    if (z < 2) {
        short* __restrict__ O = (z == 0) ? Qb : Kb;
        const float sgn = (z == 0) ? 1.0f : -1.0f;
        const float c0  = (z == 0) ? -3.0f : 0.0f;     // fold 1/8 into Q
        float l2gj[4];
        #pragma unroll
        for (int j = 0; j < 4; ++j) {
            int hh = (n0 + wc + j * 16 + lr) >> 6;
            l2gj[j] = sgn * log2f(1.0f - exp2f(-5.0f - (float)hh));
        }
        #pragma unroll
        for (int i = 0; i < 4; ++i) {
            int row = m0 + wr + i * 16 + lg4;
            #pragma unroll
            for (int j = 0; j < 4; ++j) {
                int col = n0 + wc + j * 16 + lr;
                #pragma unroll
                for (int r = 0; r < 4; ++r) {
                    int tl = (row + r) & 63;
                    float fac = exp2f(fmaf(l2gj[j], (float)tl, c0));
                    O[(size_t)(row + r) * DM + col] = f2bf(acc[i][j][r] * fac);
                }
            }
        }
    } else {
        #pragma unroll
        for (int i = 0; i < 4; ++i) {
            int row  = m0 + wr + i * 16 + lg4;
            int bidx = row >> 11, tb = row & (TSEQ - 1);
            #pragma unroll
            for (int j = 0; j < 4; ++j) {
                int col = n0 + wc + j * 16 + lr;
                v4s pk;
                #pragma unroll
                for (int r = 0; r < 4; ++r) pk[r] = f2bf(acc[i][j][r]);
                *(v4s*)(Vt + ((size_t)bidx << 21) + ((size_t)col << 11) + tb) = pk;
            }
        }
    }
}

// ---------------------------------------------------------------------------
// Retention, block-cooperative staged version.
// Block = (b, h, band-pair): bands vA=kp and vB=31-kp, each 64 rows; the 4
// waves each own 16 rows of the band.  Per j-tile iter, the block stages the
// shared K-tile (64x64) + Vt-tile (64x64) into LDS once via global_load_lds
// (linear dest + pre-swizzled source), double-buffered, one vmcnt(0)+barrier
// per iter (2-phase pipeline).  Every block does exactly 33 iters (v+1 +
// 32-v) -> perfectly balanced.  Decay prescaled into Q'/K'; per-tile residual
// is the uniform scalar tf (*= gamma^64 per step).  Swapped QK -> cvt_pk +
// b64 swizzled per-wave S strip -> PV (Y^T = V^T . S) from the same staged
// LDS.  grid(512): xcd = bid&7, 4 (b,h) per XCD for L2 locality.
// ---------------------------------------------------------------------------
__global__ __launch_bounds__(256) void retention_mfma(
    const short* __restrict__ Qb, const short* __restrict__ Kb,
    const short* __restrict__ Vt, float* __restrict__ Y,
    float* __restrict__ stats)
{
    const int bid = blockIdx.x;               // 0..511
    const int xcd = bid & 7, rblk = bid >> 3; // 64 blocks per XCD
    const int bh  = xcd * 4 + (rblk >> 4);    // 0..31, 4 (b,h) per XCD
    const int kp  = rblk & 15;                // band-pair index 0..15
    const int b = bh >> 4, h = bh & 15;
    const int tid = threadIdx.x, l = tid & 63, w = tid >> 6;
    const int lr = l & 15, g = l >> 4;
    const int vA = kp, vB = 31 - kp;

    __shared__ short stage[2][128 * 64];      // 32 KB: rows 0-63 K, 64-127 Vt
    __shared__ short S_lds[4][16 * 64];       // 8 KB per-wave S strips
    __shared__ float tr[4][16][68];           // 17.4 KB epilogue transpose

    const float l2g = log2f(1.0f - exp2f(-5.0f - (float)h));
    const float g64 = exp2f(l2g * 64.0f);     // gamma^64

    const size_t kroot = (size_t)(b * TSEQ) * DM + h * DH;
    const size_t vroot = ((size_t)b * DM + h * DH) * TSEQ;
    const char* Kg = (const char*)(Kb + kroot);
    const char* Vg = (const char*)(Vt + vroot);

    // staging descriptors: 4 chunks/thread; dest linear, source pre-swizzled
    const char* gbase[4]; int jmul[4]; int sdst[4];
    #pragma unroll
    for (int p = 0; p < 4; ++p) {
        int row = p * 32 + (tid >> 3);         // 0..127
        int sw  = ((tid & 7) * 16) ^ ((row & 7) << 4);
        if (row < 64) { gbase[p] = Kg + (size_t)row * (DM * 2) + sw; jmul[p] = DM * 2; }
        else          { gbase[p] = Vg + (size_t)(row - 64) * (TSEQ * 2) + sw; jmul[p] = 2; }
        sdst[p] = (p * 256 + (tid & 192)) * 16;
    }

    const int swz = (lr & 7) << 4;
    char* Sw = (char*)S_lds[w];

    int cur = 0;
    // prologue: stage first tile (band A diag)
    {
        char* dst = (char*)stage[0];
        #pragma unroll
        for (int p = 0; p < 4; ++p)
            gl_lds16(gbase[p] + (size_t)(vA * 64) * jmul[p], dst + sdst[p]);
    }
    asm volatile("s_waitcnt vmcnt(0)" ::: "memory");
    __syncthreads();

    float lsum = 0.f, lsq = 0.f;

    #pragma unroll 1
    for (int band = 0; band < 2; ++band) {
        const int v   = band ? vB : vA;
        const int i0w = v * 64 + w * 16;

        const short* qp = Qb + kroot + (size_t)(i0w + lr) * DM;
        v8s qf0 = *(const v8s*)(qp + g * 8);
        v8s qf1 = *(const v8s*)(qp + 32 + g * 8);

        v4f y[4];
        #pragma unroll
        for (int dt = 0; dt < 4; ++dt) y[dt] = (v4f){0.f, 0.f, 0.f, 0.f};

        float tf = 1.0f;                       // gamma^(64*(v-jt))
        #pragma unroll 1
        for (int jt = v; jt >= 0; --jt) {
            // stage next tile (flat sequence across the band switch)
            const int nj = (jt > 0) ? (jt - 1) * 64
                                    : (band == 0 ? vB * 64 : -1);
            if (nj >= 0) {
                char* dst = (char*)stage[cur ^ 1];
                #pragma unroll
                for (int p = 0; p < 4; ++p)
                    gl_lds16(gbase[p] + (size_t)nj * jmul[p], dst + sdst[p]);
            }

            const char* SB = (const char*)stage[cur];
            const int j0 = jt * 64;
            const bool dg = (jt == v);

            // ---- St = K'.Q'^T (A = staged K rows j, B = Q regs) ----
            v4f st[4];
            #pragma unroll
            for (int n = 0; n < 4; ++n) {
                int krow = n * 16 + lr;
                int rs = (krow & 7) << 4;
                v8s kf0 = *(const v8s*)(SB + krow * 128 + ((g * 16) ^ rs));
                v8s kf1 = *(const v8s*)(SB + krow * 128 + ((64 + g * 16) ^ rs));
                v4f a = (v4f){0.f, 0.f, 0.f, 0.f};
                a = __builtin_amdgcn_mfma_f32_16x16x32_bf16(kf0, qf0, a, 0, 0, 0);
                a = __builtin_amdgcn_mfma_f32_16x16x32_bf16(kf1, qf1, a, 0, 0, 0);
                st[n] = a;
            }

            // ---- uniform tile decay + diag mask + pack -> swizzled S strip ----
            #pragma unroll
            for (int n = 0; n < 4; ++n) {
                v4f vv = st[n] * tf;
                if (dg) {
                    #pragma unroll
                    for (int r = 0; r < 4; ++r)
                        if ((i0w + lr) - (j0 + n * 16 + g * 4 + r) < 0)
                            vv[r] = 0.0f;
                }
                unsigned u0 = cvtpk_bf16(vv[0], vv[1]);
                unsigned u1 = cvtpk_bf16(vv[2], vv[3]);
                int byte = (lr * 128 + n * 32 + g * 8) ^ swz;
                *(unsigned long long*)(Sw + byte) =
                    (unsigned long long)u0 | ((unsigned long long)u1 << 32);
            }

            // ---- Y^T += V^T . S (A = staged Vt rows d, B = S strip) ----
            v8s sB0 = *(const v8s*)(Sw + ((lr * 128 + g * 16) ^ swz));
            v8s sB1 = *(const v8s*)(Sw + ((lr * 128 + 64 + g * 16) ^ swz));
            #pragma unroll
            for (int dt = 0; dt < 4; ++dt) {
                int vrow = 64 + dt * 16 + lr;
                int rs = (vrow & 7) << 4;
                v8s vf0 = *(const v8s*)(SB + vrow * 128 + ((g * 16) ^ rs));
                v8s vf1 = *(const v8s*)(SB + vrow * 128 + ((64 + g * 16) ^ rs));
                y[dt] = __builtin_amdgcn_mfma_f32_16x16x32_bf16(vf0, sB0, y[dt], 0, 0, 0);
                y[dt] = __builtin_amdgcn_mfma_f32_16x16x32_bf16(vf1, sB1, y[dt], 0, 0, 0);
            }

            asm volatile("s_waitcnt vmcnt(0)" ::: "memory");
            __syncthreads();
            cur ^= 1;
            tf *= g64;
        }

        // ---- band epilogue: GN stats + un-transpose + Y store ----
        #pragma unroll
        for (int dt = 0; dt < 4; ++dt)
            #pragma unroll
            for (int r = 0; r < 4; ++r) {
                float vy = y[dt][r];
                lsum += vy; lsq += vy * vy;
            }

        #pragma unroll
        for (int dt = 0; dt < 4; ++dt)
            #pragma unroll
            for (int r = 0; r < 4; ++r)
                tr[w][lr][dt * 16 + g * 4 + r] = y[dt][r];
        __builtin_amdgcn_sched_barrier(0);
        #pragma unroll
        for (int u = 0; u < 4; ++u) {
            v4f val = *(const v4f*)&tr[w][lr][g * 16 + u * 4];
            *(v4f*)&Y[(size_t)(b * TSEQ + i0w + lr) * DM + h * DH + g * 16 + u * 4] = val;
        }
        __builtin_amdgcn_sched_barrier(0);
    }

    // ---- per-wave stats -> atomics ----
    #pragma unroll
    for (int m = 32; m; m >>= 1) {
        lsum += __shfl_xor(lsum, m, 64);
        lsq  += __shfl_xor(lsq,  m, 64);
    }
    if (l == 0) {
        atomicAdd(&stats[b * NH + h],      lsum);
        atomicAdd(&stats[32 + b * NH + h], lsq);
    }
}

// ---------------------------------------------------------------------------
// GroupNorm finalize: per (b, channel) scale/shift
// ---------------------------------------------------------------------------
__global__ __launch_bounds__(256) void gn_finalize(
    const float* __restrict__ stats,
    const float* __restrict__ gnw, const float* __restrict__ gnb,
    float* __restrict__ scale, float* __restrict__ shift)
{
    int idx = blockIdx.x * 256 + threadIdx.x;
    if (idx >= NB * DM) return;
    int bb = idx >> 10;
    int c  = idx & (DM - 1);
    int hh = c >> 6;
    const float n = (float)(DH * TSEQ);
    float mean = stats[bb * NH + hh] / n;
    float var  = stats[32 + bb * NH + hh] / n - mean * mean;
    float rstd = rsqrtf(var + GN_EPS);
    float sc = rstd * gnw[c];
    scale[idx] = sc;
    shift[idx] = gnb[c] - mean * sc;
}

// ---------------------------------------------------------------------------
// Apply GN -> bf16 (input to the output projection)
// ---------------------------------------------------------------------------
__global__ __launch_bounds__(256) void gn_apply(
    const float* __restrict__ Y, const float* __restrict__ scale,
    const float* __restrict__ shift, short* __restrict__ Ybf)
{
    const int total4 = (NB * TSEQ * DM) / 4;   // 1,048,576
    for (int i = blockIdx.x * 256 + threadIdx.x; i < total4;
         i += gridDim.x * 256) {
        int e = i * 4;
        int c = e & (DM - 1);
        int bb = e >> 21;
        v4f yv = *(const v4f*)(Y + e);
        v4f sc = *(const v4f*)(scale + bb * DM + c);
        v4f sh = *(const v4f*)(shift + bb * DM + c);
        v4s o;
        #pragma unroll
        for (int j = 0; j < 4; ++j) o[j] = f2bf(yv[j] * sc[j] + sh[j]);
        *(v4s*)(Ybf + e) = o;
    }
}

// ---------------------------------------------------------------------------
// Output projection: out = Ybf @ Wo^T, fp32 out.  Same m97-style main loop.
// ---------------------------------------------------------------------------
__global__ __launch_bounds__(256, 3) void gemm_out_mfma(
    const short* __restrict__ Ybf, const short* __restrict__ Wob,
    float* __restrict__ out)
{
    const int n0 = blockIdx.x * 128, m0 = blockIdx.y * 128;
    const int t = threadIdx.x, l = t & 63, w = t >> 6;
    const int wr = (w >> 1) * 64, wc = (w & 1) * 64;
    const int lr = l & 15, g = l >> 4;

    __shared__ short As[128 * 64];
    __shared__ short Bs[128 * 64];

    v4f acc[4][4];
    #pragma unroll
    for (int i = 0; i < 4; ++i)
        #pragma unroll
        for (int j = 0; j < 4; ++j) acc[i][j] = (v4f){0.f, 0.f, 0.f, 0.f};

    const char* Agp = (const char*)(Ybf + (size_t)m0 * DM);
    const char* Bgp = (const char*)(Wob + (size_t)n0 * DM);

    int soff[4], sdst[4];
    #pragma unroll
    for (int p = 0; p < 4; ++p) {
        int i = p * 256 + t;
        int row = i >> 3;
        int cp  = (i & 7) * 16;
        soff[p] = row * (DM * 2) + (cp ^ ((row & 7) << 4));
        sdst[p] = (p * 256 + (t & 192)) * 16;
    }
    const int swz = (lr & 7) << 4;

    for (int kt = 0; kt < DM / 64; ++kt) {
        const int kb = kt * 128;
        #pragma unroll
        for (int p = 0; p < 4; ++p) {
            gl_lds16(Agp + (size_t)soff[p] + kb, (char*)As + sdst[p]);
            gl_lds16(Bgp + (size_t)soff[p] + kb, (char*)Bs + sdst[p]);
        }
        asm volatile("s_waitcnt vmcnt(0)" ::: "memory");
        __syncthreads();

        v8s bfr[4][2];
        #pragma unroll
        for (int j = 0; j < 4; ++j) {
            int rowb = wc + j * 16 + lr;
            #pragma unroll
            for (int ks = 0; ks < 2; ++ks)
                bfr[j][ks] = *(const v8s*)((const char*)Bs + rowb * 128
                               + ((ks * 64 + g * 16) ^ swz));
        }
        #pragma unroll
        for (int i = 0; i < 4; ++i) {
            int rowa = wr + i * 16 + lr;
            v8s a0 = *(const v8s*)((const char*)As + rowa * 128 + ((g * 16) ^ swz));
            v8s a1 = *(const v8s*)((const char*)As + rowa * 128 + ((64 + g * 16) ^ swz));
            #pragma unroll
            for (int j = 0; j < 4; ++j) {
                acc[i][j] = __builtin_amdgcn_mfma_f32_16x16x32_bf16(
                    a0, bfr[j][0], acc[i][j], 0, 0, 0);
                acc[i][j] = __builtin_amdgcn_mfma_f32_16x16x32_bf16(
                    a1, bfr[j][1], acc[i][j], 0, 0, 0);
            }
        }
        __syncthreads();
    }

    #pragma unroll
    for (int i = 0; i < 4; ++i) {
        int row = m0 + wr + i * 16 + g * 4;
        #pragma unroll
        for (int j = 0; j < 4; ++j) {
            int col = n0 + wc + j * 16 + lr;
            #pragma unroll
            for (int r = 0; r < 4; ++r)
                out[(size_t)(row + r) * DM + col] = acc[i][j][r];
        }
    }
}

// ---------------------------------------------------------------------------
extern "C" void kernel_launch(void* const* d_in, const int* in_sizes, int n_in,
                              void* d_out, int out_size, void* d_ws, size_t ws_size,
                              hipStream_t stream)
{
    const float* x   = (const float*)d_in[0];
    const float* Wq  = (const float*)d_in[1];
    const float* Wk  = (const float*)d_in[2];
    const float* Wv  = (const float*)d_in[3];
    const float* Wo  = (const float*)d_in[4];
    const float* gnw = (const float*)d_in[5];
    const float* gnb = (const float*)d_in[6];
    float* out = (float*)d_out;

    // workspace carve (bytes)
    char* wsb = (char*)d_ws;
    size_t o = 0;
    float* Y    = (float*)(wsb + o); o += (size_t)NB * TSEQ * DM * 4;
    short* Qb   = (short*)(wsb + o); o += (size_t)NB * TSEQ * DM * 2;
    short* Kb   = (short*)(wsb + o); o += (size_t)NB * TSEQ * DM * 2;
    short* Vt   = (short*)(wsb + o); o += (size_t)NB * TSEQ * DM * 2;
    short* xbf  = (short*)(wsb + o); o += (size_t)NB * TSEQ * DM * 2;
    short* wbf  = (short*)(wsb + o); o += (size_t)4 * DM * DM * 2;
    short* Ybf  = (short*)(wsb + o); o += (size_t)NB * TSEQ * DM * 2;
    float* stats = (float*)(wsb + o); o += 256;
    float* scale = (float*)(wsb + o); o += (size_t)NB * DM * 4;
    float* shift = (float*)(wsb + o); o += (size_t)NB * DM * 4;
    if (ws_size < o) return;

    cast_kernel<<<2048, 256, 0, stream>>>(x, Wq, Wk, Wv, Wo, xbf, wbf, stats);
    gemm_qkv_mfma<<<dim3(DM / 128, (NB * TSEQ) / 128, 3), 256, 0, stream>>>(
        xbf, wbf, Qb, Kb, Vt);
    retention_mfma<<<dim3(512), 256, 0, stream>>>(
        Qb, Kb, Vt, Y, stats);
    gn_finalize<<<dim3((NB * DM + 255) / 256), 256, 0, stream>>>(
        stats, gnw, gnb, scale, shift);
    gn_apply<<<2048, 256, 0, stream>>>(Y, scale, shift, Ybf);
    gemm_out_mfma<<<dim3(DM / 128, (NB * TSEQ) / 128), 256, 0, stream>>>(
        Ybf, wbf + 3 * (size_t)DM * DM, out);
}